// Round 10
// baseline (225.732 us; speedup 1.0000x reference)
//
#include <hip/hip_runtime.h>

#define NB   16
#define NSQ  1024
#define NSKV 1024
#define ND   256

typedef __bf16    bf16x8 __attribute__((ext_vector_type(8)));
typedef float     f32x4  __attribute__((ext_vector_type(4)));
typedef _Float16  f16x4  __attribute__((ext_vector_type(4)));

#define KST 264   // LDS K-row stride in bf16/f16 elems (528 B; 2-way bank alias = free)

// ---- prep 1: K (f32) -> bf16 row-major ----
__global__ __launch_bounds__(256) void cvt_k_bf16(
    const float* __restrict__ src, __bf16* __restrict__ dst)
{
    const int i = blockIdx.x * 256 + threadIdx.x;
    const float4* s = (const float4*)src + (size_t)i * 2;
    float4 a = s[0], b = s[1];
    bf16x8 o;
    o[0] = (__bf16)a.x; o[1] = (__bf16)a.y; o[2] = (__bf16)a.z; o[3] = (__bf16)a.w;
    o[4] = (__bf16)b.x; o[5] = (__bf16)b.y; o[6] = (__bf16)b.z; o[7] = (__bf16)b.w;
    ((bf16x8*)dst)[i] = o;
}

// ---- prep 2: pack mask to bits ----
// mw[row*64 + h*16 + m], bit c = (mask[row][h*256 + c*16 + m] != 0).
__global__ __launch_bounds__(256) void pack_mask(
    const int* __restrict__ mask, unsigned* __restrict__ mw)
{
    const int row = blockIdx.x * 4 + (threadIdx.x >> 6);   // b*NSQ + q
    const int l   = threadIdx.x & 63;
    const int4* mrow = (const int4*)(mask + (size_t)row * NSKV) + l * 4;
    unsigned w = 0;
    #pragma unroll
    for (int v = 0; v < 4; ++v) {
        int4 mv = mrow[v];
        w |= (mv.x != 0 ? 1u : 0u) << (v * 4 + 0);
        w |= (mv.y != 0 ? 1u : 0u) << (v * 4 + 1);
        w |= (mv.z != 0 ? 1u : 0u) << (v * 4 + 2);
        w |= (mv.w != 0 ? 1u : 0u) << (v * 4 + 3);
    }
    const int m    = l & 15;
    const int base = l & 48;
    unsigned out = 0;
    #pragma unroll
    for (int c = 0; c < 16; ++c) {
        unsigned v = (unsigned)__shfl((int)w, base | c);
        out |= ((v >> m) & 1u) << c;
    }
    mw[(size_t)row * 64 + l] = out;
}

// ---- main fused kernel ----
// Block = 256 thr (4 waves) = one 16-q-row tile; wave h owns k-quarter
// [h*256,+256). Depth-1 wave-private pipeline on a SINGLE 16-row LDS
// buffer per wave: LDC(c+1) issues global loads, CMP(c) ds_reads chunk c,
// STC(c+1) ds_writes over the same buffer. LDS pipe is in-order within a
// wave, so the reads (earlier in program order) can't be clobbered.
// LDS = 33.8 KB -> 4 blocks/CU, 4 waves/SIMD (2x R7's TLP for latency
// cover). e parks in f16 regs; staging LDS reused post-loop as the
// transpose buffer for coalesced 1KB p-stores.
__global__ __launch_bounds__(256, 4) void attn_fused(
    const float* __restrict__ Q, const __bf16* __restrict__ Kb,
    const unsigned* __restrict__ mw, float* __restrict__ out_p,
    float* __restrict__ colsum)
{
    const int b    = blockIdx.x >> 6;
    const int qt   = blockIdx.x & 63;
    const int q0   = qt * 16;
    const int tid  = threadIdx.x;
    const int lane = tid & 63;
    const int h    = tid >> 6;       // wave id = k-quarter
    const int m    = lane & 15;      // MFMA A-row / B-col / C-col
    const int kg   = lane >> 4;      // quad: d-slice for A/B, row-group for C

    __shared__ __attribute__((aligned(16))) __bf16 kbuf[4][16 * KST]; // 33.8 KB
    __shared__ float Zs[4][16];
    __shared__ float invZs[16];

    // ---- A fragments: the block's 16 Q rows, f32 -> bf16 once ----
    bf16x8 afrag[8];
    {
        const float* qbase = Q + ((size_t)(b * NSQ + q0 + m)) * ND;
        #pragma unroll
        for (int dc = 0; dc < 8; ++dc) {
            const float* p4 = qbase + dc * 32 + kg * 8;
            float4 x = *(const float4*)(p4);
            float4 y = *(const float4*)(p4 + 4);
            bf16x8 a;
            a[0] = (__bf16)x.x; a[1] = (__bf16)x.y; a[2] = (__bf16)x.z; a[3] = (__bf16)x.w;
            a[4] = (__bf16)y.x; a[5] = (__bf16)y.y; a[6] = (__bf16)y.z; a[7] = (__bf16)y.w;
            afrag[dc] = a;
        }
    }

    // ---- mask words: 4 per lane, covers the whole loop ----
    unsigned mword[4];
    #pragma unroll
    for (int i = 0; i < 4; ++i)
        mword[i] = mw[(size_t)(b * NSQ + q0 + kg * 4 + i) * 64 + h * 16 + m];

    // staging geometry: lane stages 8 x 16B; rows 2r+(lane>>5), col (lane&31)*8
    const __bf16* kq   = Kb + ((size_t)(b * NSKV + h * 256)) * ND;
    const int     gcol = (lane & 31) * 8;
    const int     grow = lane >> 5;
    __bf16* buf = &kbuf[h][0];

    float  zacc[4] = {0.f, 0.f, 0.f, 0.f};
    f16x4  ebuf[16];
    bf16x8 g[8];

    #define LDC(c) { \
        const __bf16* _p = kq + (size_t)(c) * 16 * ND + gcol; \
        _Pragma("unroll") \
        for (int r = 0; r < 8; ++r) \
            g[r] = *(const bf16x8*)(_p + (size_t)(2 * r + grow) * ND); }

    #define STC() { \
        _Pragma("unroll") \
        for (int r = 0; r < 8; ++r) \
            *(bf16x8*)(buf + (2 * r + grow) * KST + gcol) = g[r]; }

    #define CMP(c) { \
        f32x4 acc = {0.f, 0.f, 0.f, 0.f}; \
        _Pragma("unroll") \
        for (int dc = 0; dc < 8; ++dc) { \
            bf16x8 bfr = *(const bf16x8*)(buf + m * KST + dc * 32 + kg * 8); \
            acc = __builtin_amdgcn_mfma_f32_16x16x32_bf16(afrag[dc], bfr, acc, 0, 0, 0); \
        } \
        _Pragma("unroll") \
        for (int i = 0; i < 4; ++i) { \
            float e = ((mword[i] >> (c)) & 1u) ? __expf(__expf(acc[i]) * 0.0625f) : 0.f; \
            zacc[i] += e; \
            ebuf[c][i] = (_Float16)e; \
        } }

    // prologue: chunk 0 staged; then depth-1 pipeline on one buffer
    LDC(0);
    STC();
    #pragma unroll
    for (int c = 0; c < 16; ++c) {
        if (c < 15) LDC(c + 1);   // in flight across CMP below
        CMP(c);                   // ds_reads chunk c (program order precedes STC)
        if (c < 15) STC();        // waits vmcnt, ds_writes chunk c+1 over buf
    }

    // ---- park e into (now free) own-wave staging LDS for coalesced stores ----
    _Float16* myE = (_Float16*)buf;              // 16 x 264 f16 = 8448 B = buf
    #pragma unroll
    for (int c = 0; c < 16; ++c)
        #pragma unroll
        for (int i = 0; i < 4; ++i)
            myE[(kg * 4 + i) * KST + c * 16 + m] = ebuf[c][i];

    // ---- Z: reduce over 16 m-lanes, publish per-wave partials ----
    #pragma unroll
    for (int i = 0; i < 4; ++i) {
        float z = zacc[i];
        z += __shfl_xor(z, 1);
        z += __shfl_xor(z, 2);
        z += __shfl_xor(z, 4);
        z += __shfl_xor(z, 8);
        if (m == 0) Zs[h][kg * 4 + i] = z;
    }
    __syncthreads();
    if (tid < 16)
        invZs[tid] = 1.0f / (Zs[0][tid] + Zs[1][tid] + Zs[2][tid] + Zs[3][tid]);
    __syncthreads();

    // ---- write phase: full 1KB contiguous stores; colsum in-pass ----
    float csum[4] = {0.f, 0.f, 0.f, 0.f};
    float* prow = out_p + (size_t)(b * NSQ + q0) * NSKV + h * 256 + lane * 4;
    #pragma unroll
    for (int s = 0; s < 16; ++s) {
        f16x4 ev = *(const f16x4*)&myE[s * KST + lane * 4];
        const float iz = invZs[s];
        float4 pv;
        pv.x = (float)ev[0] * iz; pv.y = (float)ev[1] * iz;
        pv.z = (float)ev[2] * iz; pv.w = (float)ev[3] * iz;
        *(float4*)(prow + (size_t)s * NSKV) = pv;
        csum[0] += pv.x; csum[1] += pv.y; csum[2] += pv.z; csum[3] += pv.w;
    }
    #pragma unroll
    for (int j = 0; j < 4; ++j)
        atomicAdd(&colsum[b * NSKV + h * 256 + lane * 4 + j], csum[j]);

    #undef LDC
    #undef STC
    #undef CMP
}

// out[b,d] = sum_k colsum[b,k] * V[b,k,d]; 1024 blocks, 16 k-rows each.
__global__ __launch_bounds__(256) void attn_out_kernel(
    const float* __restrict__ colsum, const float* __restrict__ V,
    float* __restrict__ out)
{
    const int b  = blockIdx.x >> 6;
    const int ks = (blockIdx.x & 63) << 4;
    const int d  = threadIdx.x;
    float acc = 0.f;
    #pragma unroll
    for (int k = 0; k < 16; ++k) {
        acc += colsum[b * NSKV + ks + k] * V[((size_t)(b * NSKV + ks + k)) * ND + d];
    }
    atomicAdd(&out[b * ND + d], acc);
}

extern "C" void kernel_launch(void* const* d_in, const int* in_sizes, int n_in,
                              void* d_out, int out_size, void* d_ws, size_t ws_size,
                              hipStream_t stream)
{
    (void)in_sizes; (void)n_in; (void)out_size; (void)ws_size;
    const float* Q    = (const float*)d_in[0];
    const float* K    = (const float*)d_in[1];
    const float* V    = (const float*)d_in[2];
    const int*   mask = (const int*)d_in[3];

    float* out0 = (float*)d_out;            // (B, D) = 4096 floats
    float* p    = out0 + NB * ND;           // p_attn (B, SQ, SKV)

    float*    colsum = (float*)d_ws;                               // 64 KB
    __bf16*   Kb     = (__bf16*)((char*)d_ws + (64 << 10));        // 8.4 MB
    unsigned* mwbits = (unsigned*)((char*)d_ws + (64 << 10) + (size_t)NB * NSKV * ND * 2); // 4.2 MB

    hipMemsetAsync(colsum, 0, NB * NSKV * sizeof(float), stream);
    hipMemsetAsync(out0, 0, NB * ND * sizeof(float), stream);

    const int nK8 = NB * NSKV * ND / 8;
    cvt_k_bf16<<<nK8 / 256, 256, 0, stream>>>(K, Kb);
    pack_mask<<<NB * NSQ / 4, 256, 0, stream>>>(mask, mwbits);
    attn_fused<<<NB * 64, 256, 0, stream>>>(Q, Kb, mwbits, p, colsum);
    attn_out_kernel<<<NB * 64, 256, 0, stream>>>(colsum, V, out0);
}

// Round 11
// 201.791 us; speedup vs baseline: 1.1186x; 1.1186x over previous
//
#include <hip/hip_runtime.h>

#define NB   16
#define NSQ  1024
#define NSKV 1024
#define ND   256

typedef __bf16    bf16x8 __attribute__((ext_vector_type(8)));
typedef float     f32x4  __attribute__((ext_vector_type(4)));
typedef _Float16  f16x4  __attribute__((ext_vector_type(4)));

#define KST 264   // LDS K-row stride in bf16/f16 elems (528 B)

// ---- merged prep: cvt K->bf16 | pack mask bits | zero colsum | zero out0 ----
// grid = 2048 + 4096 + 64 + 16 = 6224 blocks x 256 thr; branch is block-uniform.
__global__ __launch_bounds__(256) void prep_kernel(
    const float* __restrict__ K, __bf16* __restrict__ Kb,
    const int* __restrict__ mask, unsigned* __restrict__ mw,
    float* __restrict__ colsum, float* __restrict__ out0)
{
    const int bid = blockIdx.x;
    const int tid = threadIdx.x;
    if (bid < 2048) {
        // K (f32) -> bf16 row-major; one bf16x8 per thread
        const int i = bid * 256 + tid;
        const float4* s = (const float4*)K + (size_t)i * 2;
        float4 a = s[0], b = s[1];
        bf16x8 o;
        o[0] = (__bf16)a.x; o[1] = (__bf16)a.y; o[2] = (__bf16)a.z; o[3] = (__bf16)a.w;
        o[4] = (__bf16)b.x; o[5] = (__bf16)b.y; o[6] = (__bf16)b.z; o[7] = (__bf16)b.w;
        ((bf16x8*)Kb)[i] = o;
    } else if (bid < 2048 + 4096) {
        // mask -> bits: mw[row*64 + h*16 + m], bit c = mask[row][h*256+c*16+m]!=0
        const int row = (bid - 2048) * 4 + (tid >> 6);
        const int l   = tid & 63;
        const int4* mrow = (const int4*)(mask + (size_t)row * NSKV) + l * 4;
        unsigned w = 0;
        #pragma unroll
        for (int v = 0; v < 4; ++v) {
            int4 mv = mrow[v];
            w |= (mv.x != 0 ? 1u : 0u) << (v * 4 + 0);
            w |= (mv.y != 0 ? 1u : 0u) << (v * 4 + 1);
            w |= (mv.z != 0 ? 1u : 0u) << (v * 4 + 2);
            w |= (mv.w != 0 ? 1u : 0u) << (v * 4 + 3);
        }
        const int m    = l & 15;
        const int base = l & 48;
        unsigned out = 0;
        #pragma unroll
        for (int c = 0; c < 16; ++c) {
            unsigned v = (unsigned)__shfl((int)w, base | c);
            out |= ((v >> m) & 1u) << c;
        }
        mw[(size_t)row * 64 + l] = out;
    } else if (bid < 2048 + 4096 + 64) {
        colsum[(bid - 6144) * 256 + tid] = 0.f;
    } else {
        out0[(bid - 6208) * 256 + tid] = 0.f;
    }
}

// ---- main fused kernel ----
// Block = 256 thr (4 waves) = one 16-q-row tile; wave h owns k-quarter
// [h*256,+256). R7's two-buffer wave-private pipeline (no barriers in the
// main loop), DEPTH-2: chunk c's global loads issue TWO computes before its
// ds_write. Both register sets (ga, gb) stay live across the computes —
// VGPR ~112+ is the success signature (compiler held the lookahead).
// e parks in f16 regs; staging LDS reused post-loop as the transpose
// buffer for coalesced 1KB p-stores.
__global__ __launch_bounds__(256, 2) void attn_fused(
    const float* __restrict__ Q, const __bf16* __restrict__ Kb,
    const unsigned* __restrict__ mw, float* __restrict__ out_p,
    float* __restrict__ colsum)
{
    const int b    = blockIdx.x >> 6;
    const int qt   = blockIdx.x & 63;
    const int q0   = qt * 16;
    const int tid  = threadIdx.x;
    const int lane = tid & 63;
    const int h    = tid >> 6;       // wave id = k-quarter
    const int m    = lane & 15;      // MFMA A-row / B-col / C-col
    const int kg   = lane >> 4;      // quad: d-slice for A/B, row-group for C

    __shared__ __attribute__((aligned(16))) __bf16 kbuf[4][2][16 * KST]; // 67.6 KB
    __shared__ float Zs[4][16];
    __shared__ float invZs[16];

    // ---- A fragments: the block's 16 Q rows, f32 -> bf16 once ----
    bf16x8 afrag[8];
    {
        const float* qbase = Q + ((size_t)(b * NSQ + q0 + m)) * ND;
        #pragma unroll
        for (int dc = 0; dc < 8; ++dc) {
            const float* p4 = qbase + dc * 32 + kg * 8;
            float4 x = *(const float4*)(p4);
            float4 y = *(const float4*)(p4 + 4);
            bf16x8 a;
            a[0] = (__bf16)x.x; a[1] = (__bf16)x.y; a[2] = (__bf16)x.z; a[3] = (__bf16)x.w;
            a[4] = (__bf16)y.x; a[5] = (__bf16)y.y; a[6] = (__bf16)y.z; a[7] = (__bf16)y.w;
            afrag[dc] = a;
        }
    }

    // ---- mask words: 4 per lane, covers the whole loop ----
    unsigned mword[4];
    #pragma unroll
    for (int i = 0; i < 4; ++i)
        mword[i] = mw[(size_t)(b * NSQ + q0 + kg * 4 + i) * 64 + h * 16 + m];

    // staging geometry: lane stages 8 x 16B; rows 2r+(lane>>5), col (lane&31)*8
    const __bf16* kq   = Kb + ((size_t)(b * NSKV + h * 256)) * ND;
    const int     gcol = (lane & 31) * 8;
    const int     grow = lane >> 5;
    __bf16* buf0 = &kbuf[h][0][0];
    __bf16* buf1 = &kbuf[h][1][0];

    float  zacc[4] = {0.f, 0.f, 0.f, 0.f};
    f16x4  ebuf[16];
    bf16x8 ga[8], gb[8];

    #define LDCHUNK(g, c) { \
        const __bf16* _p = kq + (size_t)(c) * 16 * ND + gcol; \
        _Pragma("unroll") \
        for (int r = 0; r < 8; ++r) \
            (g)[r] = *(const bf16x8*)(_p + (size_t)(2 * r + grow) * ND); }

    #define STCHUNK(g, buf) { \
        _Pragma("unroll") \
        for (int r = 0; r < 8; ++r) \
            *(bf16x8*)((buf) + (2 * r + grow) * KST + gcol) = (g)[r]; }

    #define COMPUTE(buf, c) { \
        f32x4 acc = {0.f, 0.f, 0.f, 0.f}; \
        _Pragma("unroll") \
        for (int dc = 0; dc < 8; ++dc) { \
            bf16x8 bfr = *(const bf16x8*)((buf) + m * KST + dc * 32 + kg * 8); \
            acc = __builtin_amdgcn_mfma_f32_16x16x32_bf16(afrag[dc], bfr, acc, 0, 0, 0); \
        } \
        _Pragma("unroll") \
        for (int i = 0; i < 4; ++i) { \
            float e = ((mword[i] >> (c)) & 1u) ? __expf(__expf(acc[i]) * 0.0625f) : 0.f; \
            zacc[i] += e; \
            ebuf[c][i] = (_Float16)e; \
        } }

    // prologue: chunks 0,1 in flight; chunk 0 staged
    LDCHUNK(ga, 0);
    LDCHUNK(gb, 1);
    STCHUNK(ga, buf0);

    #pragma unroll
    for (int cc = 0; cc < 16; cc += 2) {
        if (cc + 2 < 16) LDCHUNK(ga, cc + 2);   // 2 COMPUTEs before its STCHUNK
        COMPUTE(buf0, cc);
        STCHUNK(gb, buf1);                      // chunk cc+1 (loaded 2 CMPs ago)
        if (cc + 3 < 16) LDCHUNK(gb, cc + 3);
        COMPUTE(buf1, cc + 1);
        if (cc + 2 < 16) STCHUNK(ga, buf0);     // chunk cc+2
    }

    // ---- park e into (now free) own-wave staging LDS for coalesced stores ----
    _Float16* myE = (_Float16*)&kbuf[h][0][0];   // 16 x 264 f16 = 8448 B
    #pragma unroll
    for (int c = 0; c < 16; ++c)
        #pragma unroll
        for (int i = 0; i < 4; ++i)
            myE[(kg * 4 + i) * KST + c * 16 + m] = ebuf[c][i];

    // ---- Z: reduce over 16 m-lanes, publish per-wave partials ----
    #pragma unroll
    for (int i = 0; i < 4; ++i) {
        float z = zacc[i];
        z += __shfl_xor(z, 1);
        z += __shfl_xor(z, 2);
        z += __shfl_xor(z, 4);
        z += __shfl_xor(z, 8);
        if (m == 0) Zs[h][kg * 4 + i] = z;
    }
    __syncthreads();
    if (tid < 16)
        invZs[tid] = 1.0f / (Zs[0][tid] + Zs[1][tid] + Zs[2][tid] + Zs[3][tid]);
    __syncthreads();

    // ---- write phase: full 1KB contiguous stores; colsum in-pass ----
    float csum[4] = {0.f, 0.f, 0.f, 0.f};
    float* prow = out_p + (size_t)(b * NSQ + q0) * NSKV + h * 256 + lane * 4;
    #pragma unroll
    for (int s = 0; s < 16; ++s) {
        f16x4 ev = *(const f16x4*)&myE[s * KST + lane * 4];
        const float iz = invZs[s];
        float4 pv;
        pv.x = (float)ev[0] * iz; pv.y = (float)ev[1] * iz;
        pv.z = (float)ev[2] * iz; pv.w = (float)ev[3] * iz;
        *(float4*)(prow + (size_t)s * NSKV) = pv;
        csum[0] += pv.x; csum[1] += pv.y; csum[2] += pv.z; csum[3] += pv.w;
    }
    #pragma unroll
    for (int j = 0; j < 4; ++j)
        atomicAdd(&colsum[b * NSKV + h * 256 + lane * 4 + j], csum[j]);

    #undef LDCHUNK
    #undef STCHUNK
    #undef COMPUTE
}

// out[b,d] = sum_k colsum[b,k] * V[b,k,d]; 1024 blocks, 16 k-rows each.
__global__ __launch_bounds__(256) void attn_out_kernel(
    const float* __restrict__ colsum, const float* __restrict__ V,
    float* __restrict__ out)
{
    const int b  = blockIdx.x >> 6;
    const int ks = (blockIdx.x & 63) << 4;
    const int d  = threadIdx.x;
    float acc = 0.f;
    #pragma unroll
    for (int k = 0; k < 16; ++k) {
        acc += colsum[b * NSKV + ks + k] * V[((size_t)(b * NSKV + ks + k)) * ND + d];
    }
    atomicAdd(&out[b * ND + d], acc);
}

extern "C" void kernel_launch(void* const* d_in, const int* in_sizes, int n_in,
                              void* d_out, int out_size, void* d_ws, size_t ws_size,
                              hipStream_t stream)
{
    (void)in_sizes; (void)n_in; (void)out_size; (void)ws_size;
    const float* Q    = (const float*)d_in[0];
    const float* K    = (const float*)d_in[1];
    const float* V    = (const float*)d_in[2];
    const int*   mask = (const int*)d_in[3];

    float* out0 = (float*)d_out;            // (B, D) = 4096 floats
    float* p    = out0 + NB * ND;           // p_attn (B, SQ, SKV)

    float*    colsum = (float*)d_ws;                               // 64 KB
    __bf16*   Kb     = (__bf16*)((char*)d_ws + (64 << 10));        // 8.4 MB
    unsigned* mwbits = (unsigned*)((char*)d_ws + (64 << 10) + (size_t)NB * NSKV * ND * 2); // 4.2 MB

    prep_kernel<<<6224, 256, 0, stream>>>(K, Kb, mask, mwbits, colsum, out0);
    attn_fused<<<NB * 64, 256, 0, stream>>>(Q, Kb, mwbits, p, colsum);
    attn_out_kernel<<<NB * 64, 256, 0, stream>>>(colsum, V, out0);
}